// Round 1
// baseline (1766.774 us; speedup 1.0000x reference)
//
#include <hip/hip_runtime.h>

// Problem constants (B=4, N=2048, C=256, H=8, D=32, keep = int(2048*0.3) = 614)
#define BDIM 4
#define NSEQ 2048
#define CDIM 256
#define NHEADS 8
#define HD 32
#define QB 8                     // query rows per block
#define NKEEP 614                // int(2048 * (1.0 - 0.7))
#define ATTN_SCALE 0.17677669529663688f  // 32^-0.5

// -------------------------------------------------------------------------
// GEMM: C[M][Nt] = A[M][K] @ W[Nt][K]^T + bias[Nt]
// BM=BN=64, BK=32, 256 threads, each thread 4x4 outputs via float4 LDS reads.
// Assumes M%64==0, Nt%64==0, K%32==0 (true for 8192/768/256 and 8192/256/256).
// -------------------------------------------------------------------------
__global__ __launch_bounds__(256) void gemm_nt_bias(
    const float* __restrict__ A, const float* __restrict__ W,
    const float* __restrict__ bias, float* __restrict__ C,
    int M, int Nt, int K)
{
    __shared__ __align__(16) float As[32][68];  // [k][m], pad 68: 16B-aligned rows, 2-way banks
    __shared__ __align__(16) float Ws[32][68];  // [k][n]
    const int tid = threadIdx.x;
    const int bm = blockIdx.x * 64;
    const int bn = blockIdx.y * 64;
    const int tm = tid >> 4;    // 0..15 -> rows tm*4..tm*4+3
    const int tn = tid & 15;    // 0..15 -> cols tn*4..tn*4+3
    const int lr = tid >> 2;    // loader row 0..63
    const int lq = tid & 3;     // loader k-subchunk (8 floats)
    const float* Ap = A + (size_t)(bm + lr) * K + lq * 8;
    const float* Wp = W + (size_t)(bn + lr) * K + lq * 8;
    float acc[4][4] = {};

    for (int k0 = 0; k0 < K; k0 += 32) {
        float4 a0 = *(const float4*)(Ap + k0);
        float4 a1 = *(const float4*)(Ap + k0 + 4);
        float4 w0 = *(const float4*)(Wp + k0);
        float4 w1 = *(const float4*)(Wp + k0 + 4);
        __syncthreads();  // prior tile reads done before overwrite
        const int kq = lq * 8;
        As[kq+0][lr]=a0.x; As[kq+1][lr]=a0.y; As[kq+2][lr]=a0.z; As[kq+3][lr]=a0.w;
        As[kq+4][lr]=a1.x; As[kq+5][lr]=a1.y; As[kq+6][lr]=a1.z; As[kq+7][lr]=a1.w;
        Ws[kq+0][lr]=w0.x; Ws[kq+1][lr]=w0.y; Ws[kq+2][lr]=w0.z; Ws[kq+3][lr]=w0.w;
        Ws[kq+4][lr]=w1.x; Ws[kq+5][lr]=w1.y; Ws[kq+6][lr]=w1.z; Ws[kq+7][lr]=w1.w;
        __syncthreads();
        #pragma unroll
        for (int k = 0; k < 32; ++k) {
            float4 av = *(const float4*)&As[k][tm*4];
            float4 wv = *(const float4*)&Ws[k][tn*4];
            acc[0][0] += av.x*wv.x; acc[0][1] += av.x*wv.y; acc[0][2] += av.x*wv.z; acc[0][3] += av.x*wv.w;
            acc[1][0] += av.y*wv.x; acc[1][1] += av.y*wv.y; acc[1][2] += av.y*wv.z; acc[1][3] += av.y*wv.w;
            acc[2][0] += av.z*wv.x; acc[2][1] += av.z*wv.y; acc[2][2] += av.z*wv.z; acc[2][3] += av.z*wv.w;
            acc[3][0] += av.w*wv.x; acc[3][1] += av.w*wv.y; acc[3][2] += av.w*wv.z; acc[3][3] += av.w*wv.w;
        }
    }
    float4 bb = *(const float4*)(bias + bn + tn*4);
    #pragma unroll
    for (int i = 0; i < 4; ++i) {
        float4 o;
        o.x = acc[i][0] + bb.x;
        o.y = acc[i][1] + bb.y;
        o.z = acc[i][2] + bb.z;
        o.w = acc[i][3] + bb.w;
        *(float4*)(C + (size_t)(bm + tm*4 + i) * Nt + bn + tn*4) = o;
    }
}

// -------------------------------------------------------------------------
// Fused sparse attention.
// qkv layout: [B][N][3][H][D] fp32 (natural output of the QKV GEMM).
// One block = QB=8 query rows of one (b,h). 256 threads (4 waves).
// Phases: scores -> exact top-k threshold (radix select, 4x 8-bit passes)
//         -> masked softmax (masked entries contribute exp(0-m)) -> PV.
// Output layout: [B][N][H*D] = [B][N][C] (ready for proj GEMM).
// -------------------------------------------------------------------------
__device__ __forceinline__ unsigned int f2key(float f) {
    unsigned int u = __float_as_uint(f);
    return (u & 0x80000000u) ? ~u : (u | 0x80000000u);  // monotone order-preserving
}

__global__ __launch_bounds__(256) void sparse_attn(
    const float* __restrict__ qkv, float* __restrict__ aout)
{
    extern __shared__ char smem[];
    float* s            = (float*)smem;                              // [QB][NSEQ]  64 KB (scores -> exp)
    unsigned int* hist  = (unsigned int*)(smem + QB*NSEQ*4);         // [QB][256]   8 KB (aliased: PV partials)
    float* q_sh         = (float*)(smem + QB*NSEQ*4 + QB*256*4);     // [QB][32]    1 KB
    unsigned int* pref  = (unsigned int*)(q_sh + QB*32);             // [QB]
    int* rem            = (int*)(pref + QB);                         // [QB]
    float* thr          = (float*)(rem + QB);                        // [QB]
    float* mrow         = thr + QB;                                  // [QB]
    float* zrow         = mrow + QB;                                 // [QB]

    const int tid = threadIdx.x;
    const int blk = blockIdx.x;
    const int nb  = NSEQ / QB;           // q-blocks per (b,h)
    const int bh  = blk / nb;
    const int qb  = blk % nb;
    const int b   = bh / NHEADS;
    const int h   = bh % NHEADS;
    const int n0  = qb * QB;
    const float* base = qkv + (size_t)b * NSEQ * (3 * CDIM);

    // --- load Q (pre-scaled) ---
    {
        int r = tid >> 5, d = tid & 31;
        q_sh[r*HD + d] = base[(size_t)(n0 + r) * 768 + h*HD + d] * ATTN_SCALE;
    }
    if (tid < QB) { pref[tid] = 0u; rem[tid] = NKEEP; }
    __syncthreads();

    // --- Phase B: scores s[r][j] = q_r . k_j (q pre-scaled) ---
    const float* kbase = base + CDIM + h*HD;
    #pragma unroll
    for (int grp = 0; grp < 2; ++grp) {
        const int j0 = grp * 1024 + tid;
        const float4* kp0 = (const float4*)(kbase + (size_t)(j0      ) * 768);
        const float4* kp1 = (const float4*)(kbase + (size_t)(j0 + 256) * 768);
        const float4* kp2 = (const float4*)(kbase + (size_t)(j0 + 512) * 768);
        const float4* kp3 = (const float4*)(kbase + (size_t)(j0 + 768) * 768);
        float acc0[QB], acc1[QB], acc2[QB], acc3[QB];
        #pragma unroll
        for (int r = 0; r < QB; ++r) { acc0[r]=0.f; acc1[r]=0.f; acc2[r]=0.f; acc3[r]=0.f; }
        #pragma unroll
        for (int c = 0; c < 8; ++c) {
            float4 k0 = kp0[c], k1 = kp1[c], k2 = kp2[c], k3 = kp3[c];
            #pragma unroll
            for (int r = 0; r < QB; ++r) {
                float4 qv = *(const float4*)&q_sh[r*HD + 4*c];
                acc0[r] += qv.x*k0.x + qv.y*k0.y + qv.z*k0.z + qv.w*k0.w;
                acc1[r] += qv.x*k1.x + qv.y*k1.y + qv.z*k1.z + qv.w*k1.w;
                acc2[r] += qv.x*k2.x + qv.y*k2.y + qv.z*k2.z + qv.w*k2.w;
                acc3[r] += qv.x*k3.x + qv.y*k3.y + qv.z*k3.z + qv.w*k3.w;
            }
        }
        #pragma unroll
        for (int r = 0; r < QB; ++r) {
            s[r*NSEQ + j0      ] = acc0[r];
            s[r*NSEQ + j0 + 256] = acc1[r];
            s[r*NSEQ + j0 + 512] = acc2[r];
            s[r*NSEQ + j0 + 768] = acc3[r];
        }
    }
    __syncthreads();

    // --- Phase C: exact 614th-largest per row via radix select on f2key ---
    // Row rr owned by lanes (tid>>5)==rr; each row's 32 lanes live in ONE wave half
    // -> wave-lockstep makes rem/pref read-then-single-lane-write race-free.
    const int rr = tid >> 5;
    const int li = tid & 31;
    for (int pass = 3; pass >= 0; --pass) {
        for (int i = tid; i < QB*256; i += 256) hist[i] = 0u;
        __syncthreads();
        const unsigned int pr   = pref[rr];
        const int shift         = pass * 8;
        const unsigned int hmsk = (pass == 3) ? 0u : (0xFFFFFFFFu << (shift + 8));
        for (int e = 0; e < 64; ++e) {
            float f = s[rr*NSEQ + li + 32*e];
            unsigned int key = f2key(f);
            if ((key & hmsk) == pr)
                atomicAdd(&hist[rr*256 + ((key >> shift) & 0xFFu)], 1u);
        }
        __syncthreads();
        // suffix scan: lane li owns bins [8*li, 8*li+8)
        unsigned int cnt[8];
        unsigned int part = 0u;
        #pragma unroll
        for (int i = 0; i < 8; ++i) { cnt[i] = hist[rr*256 + li*8 + i]; part += cnt[i]; }
        unsigned int suf = part;  // inclusive suffix over lanes >= li
        #pragma unroll
        for (int dlt = 1; dlt < 32; dlt <<= 1) {
            unsigned int v = __shfl_down(suf, dlt, 32);
            if (li + dlt < 32) suf += v;
        }
        unsigned int run = suf - part;   // count of elems in bins of lanes > li
        const int remv = rem[rr];
        #pragma unroll
        for (int i = 7; i >= 0; --i) {   // walk own bins high -> low; run = count(byte > b)
            if ((int)run < remv && remv <= (int)(run + cnt[i])) {
                rem[rr]  = remv - (int)run;
                pref[rr] = pr | ((unsigned int)(li*8 + i) << shift);
            }
            run += cnt[i];
        }
        __syncthreads();
    }
    if (tid < QB) {
        unsigned int key = pref[tid];
        unsigned int u = (key & 0x80000000u) ? (key & 0x7FFFFFFFu) : ~key;
        thr[tid] = __uint_as_float(u);
    }
    __syncthreads();

    // --- Phase D: masked softmax. masked value = 0 (attn * mask), included in softmax ---
    const float t = thr[rr];
    float lmax = 0.0f;   // >=1434 masked zeros always present
    for (int e = 0; e < 64; ++e) {
        float f  = s[rr*NSEQ + li + 32*e];
        float mv = (f >= t) ? f : 0.0f;
        lmax = fmaxf(lmax, mv);
    }
    #pragma unroll
    for (int dlt = 16; dlt >= 1; dlt >>= 1) lmax = fmaxf(lmax, __shfl_down(lmax, dlt, 32));
    if (li == 0) mrow[rr] = lmax;
    __syncthreads();
    const float m = mrow[rr];
    float lsum = 0.f;
    for (int e = 0; e < 64; ++e) {
        int idx  = rr*NSEQ + li + 32*e;
        float f  = s[idx];
        float mv = (f >= t) ? f : 0.0f;
        float ev = __expf(mv - m);
        s[idx] = ev;
        lsum += ev;
    }
    #pragma unroll
    for (int dlt = 16; dlt >= 1; dlt >>= 1) lsum += __shfl_down(lsum, dlt, 32);
    if (li == 0) zrow[rr] = lsum;
    __syncthreads();

    // --- Phase E: PV. thread = (j-group g, dim d); dense over j ---
    const int d = tid & 31;
    const int g = tid >> 5;
    const float* vbase = base + 2*CDIM + h*HD + d;
    float accv[QB];
    #pragma unroll
    for (int r = 0; r < QB; ++r) accv[r] = 0.f;
    for (int jj = 0; jj < 256; jj += 4) {
        const int j = g * 256 + jj;
        float v0 = vbase[(size_t)(j    ) * 768];
        float v1 = vbase[(size_t)(j + 1) * 768];
        float v2 = vbase[(size_t)(j + 2) * 768];
        float v3 = vbase[(size_t)(j + 3) * 768];
        #pragma unroll
        for (int r = 0; r < QB; ++r) {
            float4 p = *(const float4*)&s[r*NSEQ + j];
            accv[r] += p.x*v0 + p.y*v1 + p.z*v2 + p.w*v3;
        }
    }
    float* partial = (float*)hist;  // [8 groups][QB][32], hist no longer needed
    #pragma unroll
    for (int r = 0; r < QB; ++r) partial[(g*QB + r)*32 + d] = accv[r];
    __syncthreads();
    {
        float o = 0.f;
        #pragma unroll
        for (int g2 = 0; g2 < 8; ++g2) o += partial[(g2*QB + rr)*32 + li];
        o /= zrow[rr];
        aout[(size_t)(b*NSEQ + n0 + rr) * CDIM + h*HD + li] = o;
    }
}

// -------------------------------------------------------------------------
extern "C" void kernel_launch(void* const* d_in, const int* in_sizes, int n_in,
                              void* d_out, int out_size, void* d_ws, size_t ws_size,
                              hipStream_t stream) {
    (void)in_sizes; (void)n_in; (void)out_size; (void)ws_size;
    const float* x      = (const float*)d_in[0];
    const float* w_qkv  = (const float*)d_in[1];
    const float* b_qkv  = (const float*)d_in[2];
    const float* w_proj = (const float*)d_in[3];
    const float* b_proj = (const float*)d_in[4];
    float* out = (float*)d_out;

    const int M = BDIM * NSEQ;  // 8192
    // workspace: qkv (25.2 MB) + attn out (8.4 MB) = 33.6 MB
    float* qkv_ws  = (float*)d_ws;
    float* attn_ws = qkv_ws + (size_t)M * 768;

    // 1) QKV GEMM -> [B][N][3][H][D]
    dim3 g1(M / 64, 768 / 64);
    gemm_nt_bias<<<g1, 256, 0, stream>>>(x, w_qkv, b_qkv, qkv_ws, M, 768, 256);

    // 2) fused sparse attention -> [B][N][C]
    const size_t smem = (size_t)QB*NSEQ*4 + QB*256*4 + QB*HD*4 + QB*4*5;  // 74912 B
    (void)hipFuncSetAttribute((const void*)sparse_attn,
                              hipFuncAttributeMaxDynamicSharedMemorySize, (int)smem);
    sparse_attn<<<BDIM * NHEADS * NSEQ / QB, 256, smem, stream>>>(qkv_ws, attn_ws);

    // 3) projection GEMM -> d_out
    dim3 g2(M / 64, 256 / 64);
    gemm_nt_bias<<<g2, 256, 0, stream>>>(attn_ws, w_proj, b_proj, out, M, 256, 256);
}